// Round 5
// baseline (1453.076 us; speedup 1.0000x reference)
//
#include <hip/hip_runtime.h>
#include <cstdint>
#include <cstddef>

#define BB 256
#define TT 4096
#define ID 63
#define HH 50
#define FCD 64

typedef float f32x2 __attribute__((ext_vector_type(2)));

__device__ __forceinline__ float RLf(float v, int lane) {
    return __int_as_float(__builtin_amdgcn_readlane(__float_as_int(v), lane));
}

__device__ __forceinline__ float fast_tanh(float x) {
    // tanh(x) = 1 - 2/(e^{2x}+1); exp2 overflow -> inf -> rcp -> 0 (exact +/-1 limits)
    float e = __builtin_amdgcn_exp2f(x * 2.88539008177792681472f); // 2*log2(e)
    return 1.0f - 2.0f * __builtin_amdgcn_rcpf(e + 1.0f);
}

// =================== Phase 1: z[b,t,j] = b_ih[j]+b_hh[j] + sum_i x[b,t,i]*W_ih[j,i]
// One wave per block, 64 rows. x row held in 63 NAMED floats (no array -> no
// AGPR/scratch shuffling; rounds 1-3 lost ~5x to the allocator parking arrays
// out of arch VGPRs). W row loads are block-uniform -> s_load. z staged via LDS
// for coalesced write-out.
#define XS1(i) const float x##i = xs[lane * ID + i];
#define XS4(a,b,c,d) XS1(a) XS1(b) XS1(c) XS1(d)
#define PF4(i0,i1,i2,i3) \
    a0 = fmaf(x##i0, wp[i0], a0); a1 = fmaf(x##i1, wp[i1], a1); \
    a2 = fmaf(x##i2, wp[i2], a2); a3 = fmaf(x##i3, wp[i3], a3);

__global__ __launch_bounds__(64, 2) void proj_kernel(
    const float* __restrict__ x, const float* __restrict__ W_ih,
    const float* __restrict__ b_ih, const float* __restrict__ b_hh,
    float* __restrict__ z)
{
    __shared__ float xs[64 * ID]; // 16128 B; reused as z staging (3200 floats)
    const int lane = threadIdx.x;
    const int64_t row0 = (int64_t)blockIdx.x * 64;

    const float4* __restrict__ xin4 = (const float4*)(x + row0 * ID);
    float4* xs4 = (float4*)xs;
    for (int i = lane; i < (64 * ID) / 4; i += 64) xs4[i] = xin4[i];
    __syncthreads();

    XS4(0,1,2,3)    XS4(4,5,6,7)    XS4(8,9,10,11)   XS4(12,13,14,15)
    XS4(16,17,18,19) XS4(20,21,22,23) XS4(24,25,26,27) XS4(28,29,30,31)
    XS4(32,33,34,35) XS4(36,37,38,39) XS4(40,41,42,43) XS4(44,45,46,47)
    XS4(48,49,50,51) XS4(52,53,54,55) XS4(56,57,58,59) XS1(60) XS1(61) XS1(62)
    __syncthreads(); // xs re-used as output staging

    float* zs = xs;
#pragma unroll 1
    for (int j = 0; j < HH; ++j) {
        const float* __restrict__ wp = W_ih + j * ID; // uniform -> s_load
        float a0 = b_ih[j] + b_hh[j], a1 = 0.f, a2 = 0.f, a3 = 0.f;
        PF4(0,1,2,3)    PF4(4,5,6,7)    PF4(8,9,10,11)   PF4(12,13,14,15)
        PF4(16,17,18,19) PF4(20,21,22,23) PF4(24,25,26,27) PF4(28,29,30,31)
        PF4(32,33,34,35) PF4(36,37,38,39) PF4(40,41,42,43) PF4(44,45,46,47)
        PF4(48,49,50,51) PF4(52,53,54,55) PF4(56,57,58,59)
        a0 = fmaf(x60, wp[60], a0);
        a1 = fmaf(x61, wp[61], a1);
        a2 = fmaf(x62, wp[62], a2);
        zs[lane * HH + j] = (a0 + a2) + (a1 + a3);
    }
    __syncthreads();

    const float2* zs2 = (const float2*)zs;
    float2* __restrict__ zo2 = (float2*)(z + row0 * HH);
#pragma unroll
    for (int i = lane; i < (64 * HH) / 2; i += 64) zo2[i] = zs2[i];
}

// =================== Phase 2: sequential recurrence, one wave per batch.
// Everything register-named; packed fp32 math via elementwise_fma so the
// compiler emits v_pk_fma_f32 with an SGPR-pair broadcast of (h[2k],h[2k+1])
// and is free to place weights without AGPR copy churn (inline-asm "v"
// constraints in rounds 2-3 forced agpr<->vgpr shuttling every step).
#define WDECL(k) f32x2 w##k; w##k.x = Wrow[2*(k)]; w##k.y = Wrow[2*(k)+1];
#define MAC(k, acc) { f32x2 hh; hh.x = RLf(vh, 2*(k)); hh.y = RLf(vh, 2*(k)+1); \
                      acc = __builtin_elementwise_fma(hh, w##k, acc); }
#define STEP(zin) { \
    f32x2 aA; aA.x = (zin); aA.y = 0.f; \
    f32x2 aB; { f32x2 hh; hh.x = RLf(vh, 2); hh.y = RLf(vh, 3); aB = hh * w1; } \
    MAC(0,aA)  MAC(2,aA)  MAC(3,aB)  MAC(4,aA)  MAC(5,aB)  MAC(6,aA)  MAC(7,aB) \
    MAC(8,aA)  MAC(9,aB)  MAC(10,aA) MAC(11,aB) MAC(12,aA) MAC(13,aB) MAC(14,aA) \
    MAC(15,aB) MAC(16,aA) MAC(17,aB) MAC(18,aA) MAC(19,aB) MAC(20,aA) MAC(21,aB) \
    MAC(22,aA) MAC(23,aB) MAC(24,aA) \
    f32x2 ss = aA + aB; vh = fast_tanh(ss.x + ss.y); }

__global__ __launch_bounds__(64, 1)
__attribute__((amdgpu_waves_per_eu(1, 1)))
void rnn_kernel(
    const float* __restrict__ z, const float* __restrict__ W_hh,
    const float* __restrict__ W1, const float* __restrict__ b1,
    const float* __restrict__ W2, const float* __restrict__ b2,
    float* __restrict__ out)
{
    const int b = blockIdx.x;
    const int lane = threadIdx.x;
    const int j = (lane < HH) ? lane : (HH - 1);

    const float* __restrict__ Wrow = W_hh + j * HH;
    WDECL(0)  WDECL(1)  WDECL(2)  WDECL(3)  WDECL(4)
    WDECL(5)  WDECL(6)  WDECL(7)  WDECL(8)  WDECL(9)
    WDECL(10) WDECL(11) WDECL(12) WDECL(13) WDECL(14)
    WDECL(15) WDECL(16) WDECL(17) WDECL(18) WDECL(19)
    WDECL(20) WDECL(21) WDECL(22) WDECL(23) WDECL(24)

    const float* __restrict__ base = z + (int64_t)b * TT * HH;
    const int col = j;

    // 8-deep software pipeline of the per-step z loads (1 wave/CU: must hide
    // ~900-cycle HBM latency in-register; 8 steps x ~200 cyc covers it)
    float z0 = base[0 * HH + col], z1 = base[1 * HH + col];
    float z2 = base[2 * HH + col], z3 = base[3 * HH + col];
    float z4 = base[4 * HH + col], z5 = base[5 * HH + col];
    float z6 = base[6 * HH + col], z7 = base[7 * HH + col];
    float n0 = 0.f, n1 = 0.f, n2 = 0.f, n3 = 0.f;
    float n4 = 0.f, n5 = 0.f, n6 = 0.f, n7 = 0.f;
    const float* p = base + 8 * HH;

    float vh = 0.f;
#pragma unroll 1
    for (int t0 = 0; t0 < TT; t0 += 8) {
        if (t0 + 8 < TT) { // uniform branch; final chunk prefetches nothing
            n0 = p[0 * HH + col]; n1 = p[1 * HH + col];
            n2 = p[2 * HH + col]; n3 = p[3 * HH + col];
            n4 = p[4 * HH + col]; n5 = p[5 * HH + col];
            n6 = p[6 * HH + col]; n7 = p[7 * HH + col];
        }
        p += 8 * HH;
        STEP(z0) STEP(z1) STEP(z2) STEP(z3)
        STEP(z4) STEP(z5) STEP(z6) STEP(z7)
        z0 = n0; z1 = n1; z2 = n2; z3 = n3;
        z4 = n4; z5 = n5; z6 = n6; z7 = n7;
    }

    // ---- MLP head + argmax (softmax monotone; np.argmax tie -> 0, so strict >)
    float f = b1[lane];
#pragma unroll
    for (int k = 0; k < HH; ++k) f = fmaf(RLf(vh, k), W1[lane * HH + k], f);
    f = fmaxf(f, 0.f);
    float p0 = f * W2[lane];
    float p1 = f * W2[FCD + lane];
#pragma unroll
    for (int off = 32; off > 0; off >>= 1) {
        p0 += __shfl_down(p0, off, 64);
        p1 += __shfl_down(p1, off, 64);
    }
    if (lane == 0) out[b] = ((p1 + b2[1]) > (p0 + b2[0])) ? 1.0f : 0.0f;
}

// =================== Fallback (only if d_ws can't hold z): fused projection.
__global__ __launch_bounds__(64, 1)
__attribute__((amdgpu_waves_per_eu(1, 1)))
void rnn_fused_kernel(
    const float* __restrict__ x, const float* __restrict__ W_ih,
    const float* __restrict__ b_ih, const float* __restrict__ W_hh,
    const float* __restrict__ b_hh, const float* __restrict__ W1,
    const float* __restrict__ b1, const float* __restrict__ W2,
    const float* __restrict__ b2, float* __restrict__ out)
{
    const int b = blockIdx.x;
    const int lane = threadIdx.x;
    const int j = (lane < HH) ? lane : (HH - 1);

    const float* __restrict__ Wrow = W_hh + j * HH;
    WDECL(0)  WDECL(1)  WDECL(2)  WDECL(3)  WDECL(4)
    WDECL(5)  WDECL(6)  WDECL(7)  WDECL(8)  WDECL(9)
    WDECL(10) WDECL(11) WDECL(12) WDECL(13) WDECL(14)
    WDECL(15) WDECL(16) WDECL(17) WDECL(18) WDECL(19)
    WDECL(20) WDECL(21) WDECL(22) WDECL(23) WDECL(24)

    const float bias = b_ih[j] + b_hh[j];
    const float* __restrict__ base = x + (int64_t)b * TT * ID;
    const int col = (lane < ID) ? lane : (ID - 1);

    float vh = 0.f;
#pragma unroll 1
    for (int t = 0; t < TT; ++t) {
        float xv = base[(int64_t)t * ID + col];
        float s = bias;
#pragma unroll
        for (int i = 0; i < ID; ++i) {
            float wv = W_ih[j * ID + i];
            s = fmaf(RLf(xv, i), wv, s);
        }
        f32x2 aA; aA.x = s; aA.y = 0.f;
        f32x2 aB; { f32x2 hh; hh.x = RLf(vh, 2); hh.y = RLf(vh, 3); aB = hh * w1; }
        MAC(0,aA)  MAC(2,aA)  MAC(3,aB)  MAC(4,aA)  MAC(5,aB)  MAC(6,aA)  MAC(7,aB)
        MAC(8,aA)  MAC(9,aB)  MAC(10,aA) MAC(11,aB) MAC(12,aA) MAC(13,aB) MAC(14,aA)
        MAC(15,aB) MAC(16,aA) MAC(17,aB) MAC(18,aA) MAC(19,aB) MAC(20,aA) MAC(21,aB)
        MAC(22,aA) MAC(23,aB) MAC(24,aA)
        f32x2 ss = aA + aB; vh = fast_tanh(ss.x + ss.y);
    }

    float f = b1[lane];
#pragma unroll
    for (int k = 0; k < HH; ++k) f = fmaf(RLf(vh, k), W1[lane * HH + k], f);
    f = fmaxf(f, 0.f);
    float p0 = f * W2[lane];
    float p1 = f * W2[FCD + lane];
#pragma unroll
    for (int off = 32; off > 0; off >>= 1) {
        p0 += __shfl_down(p0, off, 64);
        p1 += __shfl_down(p1, off, 64);
    }
    if (lane == 0) out[b] = ((p1 + b2[1]) > (p0 + b2[0])) ? 1.0f : 0.0f;
}

extern "C" void kernel_launch(void* const* d_in, const int* in_sizes, int n_in,
                              void* d_out, int out_size, void* d_ws, size_t ws_size,
                              hipStream_t stream)
{
    const float* x    = (const float*)d_in[0];
    const float* W_ih = (const float*)d_in[1];
    const float* b_ih = (const float*)d_in[2];
    const float* W_hh = (const float*)d_in[3];
    const float* b_hh = (const float*)d_in[4];
    const float* W1   = (const float*)d_in[5];
    const float* b1   = (const float*)d_in[6];
    const float* W2   = (const float*)d_in[7];
    const float* b2   = (const float*)d_in[8];
    float* out = (float*)d_out;

    const size_t zbytes = (size_t)BB * TT * HH * sizeof(float);
    if (ws_size >= zbytes) {
        float* z = (float*)d_ws;
        proj_kernel<<<(BB * TT) / 64, 64, 0, stream>>>(x, W_ih, b_ih, b_hh, z);
        rnn_kernel<<<BB, 64, 0, stream>>>(z, W_hh, W1, b1, W2, b2, out);
    } else {
        rnn_fused_kernel<<<BB, 64, 0, stream>>>(x, W_ih, b_ih, W_hh, b_hh,
                                                W1, b1, W2, b2, out);
    }
}